// Round 1
// baseline (62.491 us; speedup 1.0000x reference)
//
#include <hip/hip_runtime.h>

#define HH 28
#define WW 28
#define NPIX 784
#define LWD 12
#define KLEN 25

__global__ __launch_bounds__(1024) void canny_all(
    const float* __restrict__ x, const float* __restrict__ mask,
    const float* __restrict__ g, float* __restrict__ out)
{
    __shared__ float sx[NPIX], sm[NPIX], t1x[NPIX], t1m[NPIX], sxs[NPIX], smag[NPIX];
    __shared__ unsigned rowHigh[HH], rowLow[HH], rowFinal[HH];
    __shared__ float sg[KLEN];

    const int tid = threadIdx.x;
    if (tid < KLEN) sg[tid] = g[tid];
    if (tid < HH) { rowHigh[tid] = 0u; rowLow[tid] = 0u; }
    if (tid < NPIX) { sx[tid] = x[tid]; sm[tid] = mask[tid]; }
    __syncthreads();

    const int r = tid / WW, c = tid % WW;

    // ---- Gaussian pass 1: along H (zero padding), for x and mask ----
    if (tid < NPIX) {
        float ax = 0.0f, am = 0.0f;
        #pragma unroll
        for (int i = 0; i < KLEN; ++i) {
            int rr = r + i - LWD;
            if (rr >= 0 && rr < HH) {
                float gv = sg[i];
                ax += gv * sx[rr * WW + c];
                am += gv * sm[rr * WW + c];
            }
        }
        t1x[tid] = ax; t1m[tid] = am;
    }
    __syncthreads();

    // ---- Gaussian pass 2: along W (zero padding); xs = num/(bleed+1e-12) ----
    if (tid < NPIX) {
        float ax = 0.0f, am = 0.0f;
        #pragma unroll
        for (int i = 0; i < KLEN; ++i) {
            int cc = c + i - LWD;
            if (cc >= 0 && cc < WW) {
                float gv = sg[i];
                ax += gv * t1x[r * WW + cc];
                am += gv * t1m[r * WW + cc];
            }
        }
        sxs[tid] = ax / (am + 1e-12f);
    }
    __syncthreads();

    // ---- Sobel (deriv replicate-pad, then [1,2,1] replicate-pad), mag, erosion ----
    float isob = 0.0f, jsob = 0.0f, m = 0.0f, ai = 0.0f, aj = 0.0f;
    bool er = false;
    if (tid < NPIX) {
        const int rm = (r > 0) ? r - 1 : 0, rp = (r < HH - 1) ? r + 1 : r;
        const int cm = (c > 0) ? c - 1 : 0, cp = (c < WW - 1) ? c + 1 : c;
        const float x_mm = sxs[rm * WW + cm], x_m0 = sxs[rm * WW + c], x_mp = sxs[rm * WW + cp];
        const float x_0m = sxs[r  * WW + cm],                          x_0p = sxs[r  * WW + cp];
        const float x_pm = sxs[rp * WW + cm], x_p0 = sxs[rp * WW + c], x_pp = sxs[rp * WW + cp];
        // jsob: deriv along W then smooth along H
        const float dU = x_mp - x_mm, dC = x_0p - x_0m, dD = x_pp - x_pm;
        jsob = (dU + 2.0f * dC) + dD;
        // isob: deriv along H then smooth along W
        const float hL = x_pm - x_mm, hC = x_p0 - x_m0, hR = x_pp - x_mp;
        isob = (hL + 2.0f * hC) + hR;

        const float mag2 = isob * isob + jsob * jsob;
        m = sqrtf(mag2 + 1e-9f);          // THRES=0 multiply is a no-op (m > 0 always)
        smag[tid] = m;
        ai = fabsf(isob); aj = fabsf(jsob);

        bool er2 = (r >= 1) && (r <= HH - 2) && (c >= 1) && (c <= WW - 2);
        if (er2) {
            #pragma unroll
            for (int dr = -1; dr <= 1; ++dr)
                #pragma unroll
                for (int dc = -1; dc <= 1; ++dc)
                    er2 = er2 && (sm[(r + dr) * WW + (c + dc)] != 0.0f);
        }
        er = er2 && (mag2 > 0.0f);
    }
    __syncthreads();

    // ---- Sectors, lm, outputs s0..s3, lm, test; seed hysteresis bitmasks ----
    if (tid < NPIX) {
        const bool same = ((isob >= 0.0f) && (jsob >= 0.0f)) || ((isob <= 0.0f) && (jsob <= 0.0f));
        const bool opp  = ((isob <= 0.0f) && (jsob >= 0.0f)) || ((isob >= 0.0f) && (jsob <= 0.0f));
        const float GAMMA = 0.005f;
        float s0v = 0.0f, s1v = 0.0f, s2v = 0.0f, s3v = 0.0f;
        bool lmv = false;

        // NB(dr,dc): only evaluated where er==true (interior), so always in-bounds
        #define NB(dr, dc) (smag[(r + (dr)) * WW + (c + (dc))])

        if (er && same && (ai >= aj)) {              // 0-45
            const float w  = aj / (ai + 1e-9f);
            const float ip = NB(1, 1)   * w + NB(1, 0)   * (1.0f - w);
            const float im = NB(-1, -1) * w + NB(-1, 0)  * (1.0f - w);
            const float a = fmaxf(GAMMA - m + ip, 0.0f);
            const float b = fmaxf(GAMMA - m + im, 0.0f);
            s0v = fmaxf(a, b);
            lmv = (ip <= m) && (im <= m);
        }
        if (er && same && (ai <= aj)) {              // 45-90
            const float w  = ai / aj;                // pts1 => aj >= ai and mag2>0 => aj>0
            const float ip = NB(1, 1)   * w + NB(0, 1)  * (1.0f - w);
            const float im = NB(-1, -1) * w + NB(0, -1) * (1.0f - w);
            const float a = fmaxf(GAMMA - m + ip, 0.0f);
            const float b = fmaxf(GAMMA - m + im, 0.0f);
            s1v = fmaxf(a, b);
            lmv = (ip <= m) && (im <= m);
        }
        if (er && opp && (ai <= aj)) {               // 90-135 (bug: s2 reuses ip)
            const float w  = ai / aj;
            const float ip = NB(-1, 1) * w + NB(0, 1)  * (1.0f - w);
            const float im = NB(1, -1) * w + NB(0, -1) * (1.0f - w);
            const float a = fmaxf(GAMMA - m + ip, 0.0f);
            s2v = a;                                  // max(a, a)
            lmv = (ip <= m) && (im <= m);
        }
        if (er && opp && (ai >= aj)) {               // 135-180
            const float w  = aj / ai;
            const float ip = NB(-1, 1) * w + NB(-1, 0) * (1.0f - w);
            const float im = NB(1, -1) * w + NB(1, 0)  * (1.0f - w);
            const float a = fmaxf(GAMMA - m + ip, 0.0f);
            const float b = fmaxf(GAMMA - m + im, 0.0f);
            s3v = fmaxf(a, b);
            lmv = (ip <= m) && (im <= m);
        }
        #undef NB

        out[0 * NPIX + tid] = s0v;
        out[1 * NPIX + tid] = s1v;
        out[2 * NPIX + tid] = s2v;
        out[3 * NPIX + tid] = s3v;
        out[4 * NPIX + tid] = lmv ? 1.0f : 0.0f;
        out[5 * NPIX + tid] = 1.0f;

        if (lmv && (m >= 0.2f)) atomicOr(&rowHigh[r], 1u << c);
        if (lmv && (m >= 0.1f)) atomicOr(&rowLow[r],  1u << c);
    }
    __syncthreads();

    // ---- Hysteresis: exactly 56 Jacobi iterations of (dilate & low), rows as bitmasks
    //      held one row per lane of wave 0, neighbor rows via shfl (no barriers) ----
    if (tid < 64) {
        unsigned cur = 0u, lo = 0u;
        if (tid < HH) { cur = rowHigh[tid]; lo = rowLow[tid]; }
        for (int it = 0; it < 2 * HH; ++it) {
            unsigned up = __shfl(cur, (tid + 63) & 63, 64);  // lane r-1 (wraps to zeroed lanes)
            unsigned dn = __shfl(cur, (tid + 1)  & 63, 64);  // lane r+1
            unsigned mg = up | cur | dn;
            unsigned sp = mg | (mg << 1) | (mg >> 1);
            cur = sp & lo;
        }
        if (tid < HH) rowFinal[tid] = cur;
    }
    __syncthreads();

    // ---- mag_out == mask_final exactly (mag - mag cancels) ----
    if (tid < NPIX) {
        out[6 * NPIX + tid] = (float)((rowFinal[r] >> c) & 1u);
    }
}

extern "C" void kernel_launch(void* const* d_in, const int* in_sizes, int n_in,
                              void* d_out, int out_size, void* d_ws, size_t ws_size,
                              hipStream_t stream) {
    const float* x    = (const float*)d_in[0];
    const float* mask = (const float*)d_in[1];
    const float* g    = (const float*)d_in[2];
    float* out = (float*)d_out;
    canny_all<<<1, 1024, 0, stream>>>(x, mask, g, out);
}